// Round 2
// baseline (727.641 us; speedup 1.0000x reference)
//
#include <hip/hip_runtime.h>

// ---------------------------------------------------------------------------
// SR-GNN fused implementation for MI355X / gfx950 — round 3.
//
// r2 result: 658us total; both big kernels <259us (below fill dispatches).
// r3 design:
//  - prep_all: single prep kernel (emb bf16 + all weight conversions incl.
//    W2 bf16 for MFMA phase 5b).
//  - graph_pipeline v4: edge scatter reformulated as 32x32 adjacency-matrix
//    GEMM (A_in/A_out built via LDS atomics from 64 edges, then MFMA against
//    transposed h_in/h_out). Drops the 64-iter serial loop, shM, and the m
//    conversion pass. Phase 5b (h'@W2^T) MFMA-ized. R/Z stored bf16.
//    LDS 69.6KB -> 2 blocks/CU.
//  - final_gemm v3: barrier-free streaming GEMM. No LDS; A-frags in regs,
//    B-frags direct from global (L1/L2-resident), non-temporal direct
//    stores (64B segments). Grid (16 m-tiles x 196), 4 n-tiles per block.
// ---------------------------------------------------------------------------

typedef unsigned short ushort_t;
typedef __attribute__((ext_vector_type(8))) short bf16x8;     // 8 bf16 (4 VGPR)
typedef __attribute__((ext_vector_type(4))) float f32x4;
typedef __attribute__((ext_vector_type(4))) ushort_t us4v;    // 8 B
typedef __attribute__((ext_vector_type(8))) ushort_t us8v;    // 16 B

#define HD 128
#define NPER 32
#define NGRAPH 1024
#define NNODE_V 100000
#define ETOT 65536

struct F4 { float x, y, z, w; };

__device__ __forceinline__ F4 ld4(const float* p) { return *(const F4*)p; }
__device__ __forceinline__ bf16x8 ldb8(const ushort_t* p) { return *(const bf16x8*)p; }

__device__ __forceinline__ float sigm(float x) { return 1.0f / (1.0f + __expf(-x)); }

__device__ __forceinline__ float tanh_fast(float x) {
  float ax = fabsf(x);
  float t = __expf(-2.0f * ax);
  float r = (1.0f - t) / (1.0f + t);
  return copysignf(r, x);
}

__device__ __forceinline__ ushort_t f2bf(float f) {  // RNE fp32 -> bf16
  unsigned u = __float_as_uint(f);
  u = u + 0x7FFFu + ((u >> 16) & 1u);
  return (ushort_t)(u >> 16);
}
__device__ __forceinline__ float bf2f(ushort_t b) {
  return __uint_as_float(((unsigned)b) << 16);
}
__device__ __forceinline__ us4v f2bf4(F4 v) {
  us4v o; o.x = f2bf(v.x); o.y = f2bf(v.y); o.z = f2bf(v.z); o.w = f2bf(v.w);
  return o;
}

// ---------------------------------------------------------------------------
// ws layout (bytes):
//   emb_bf  @ 0           : 100000*128*2 = 25,600,000
//   s_h     @ 25,600,000  : 1024*128*2   =    262,144
//   wih_bf  @ 25,862,144  : 384*256*2    =    196,608
//   whh_bf  @ 26,058,752  : 384*128*2    =     98,304
//   ggT_bf  @ 26,157,056  : 2*128*128*2  =     65,536   ([mat][j][k])
//   w2_bf   @ 26,222,592  : 128*128*2    =     32,768   ([j][k], no transpose
//                                                        needed: W2 is [out][in])
// ---------------------------------------------------------------------------
#define WS_EMB_OFF   0
#define WS_SH_OFF    25600000
#define WS_WIH_OFF   25862144
#define WS_WHH_OFF   26058752
#define WS_GGT_OFF   26157056
#define WS_W2T_OFF   26222592

// ---------------------------------------------------------------------------
// prep_all: blocks [0,6250) convert emb; blocks [6250,6346) convert weights.
// ---------------------------------------------------------------------------
__global__ void prep_all(const float* __restrict__ emb, ushort_t* __restrict__ emb_bf,
                         const float* __restrict__ wih, const float* __restrict__ whh,
                         const float* __restrict__ ggnn_w, const float* __restrict__ W2,
                         ushort_t* __restrict__ wih_bf, ushort_t* __restrict__ whh_bf,
                         ushort_t* __restrict__ ggT_bf, ushort_t* __restrict__ w2_bf) {
  const int b = blockIdx.x, t = threadIdx.x;
  if (b < 6250) {
    int tid = b * 256 + t;                  // 1.6M threads x 8 floats
    const float* s = emb + (size_t)tid * 8;
    F4 v0 = ld4(s), v1 = ld4(s + 4);
    us8v o;
    o.s0 = f2bf(v0.x); o.s1 = f2bf(v0.y); o.s2 = f2bf(v0.z); o.s3 = f2bf(v0.w);
    o.s4 = f2bf(v1.x); o.s5 = f2bf(v1.y); o.s6 = f2bf(v1.z); o.s7 = f2bf(v1.w);
    *(us8v*)(emb_bf + (size_t)tid * 8) = o;
    return;
  }
  int tid = (b - 6250) * 256 + t;           // 96*256 = 24576
  { F4 v = ld4(wih + tid * 4); *(us4v*)(wih_bf + tid * 4) = f2bf4(v); }
  if (tid < 12288) { F4 v = ld4(whh + tid * 4); *(us4v*)(whh_bf + tid * 4) = f2bf4(v); }
  if (tid < 16384) {                        // ggnn_w [mat][k][j] -> [mat][j][k]
    int o = tid * 2;
    int mat = o >> 14, r = o & 16383, j = r >> 7, k = r & 127;
    float v0 = ggnn_w[mat * 16384 + k * 128 + j];
    float v1 = ggnn_w[mat * 16384 + (k + 1) * 128 + j];
    unsigned pk = (unsigned)f2bf(v0) | ((unsigned)f2bf(v1) << 16);
    *(unsigned*)(ggT_bf + o) = pk;
  }
  if (tid < 4096) {                         // W2 already [j][k]
    F4 v = ld4(W2 + tid * 4); *(us4v*)(w2_bf + tid * 4) = f2bf4(v);
  }
}

// ---------------------------------------------------------------------------
// graph_pipeline v4: one block per graph.  LDS 69,632B (2 blocks/CU).
//   floats [0,4096)      : shH [32][128] fp32 (h, updated in place)
//   floats [4096,6144)   : h_bf [32][128] bf16 swz (pre-GRU h; phase4: h')
//   floats [6144,8192)   : hT_in  [128][32] bf16 swz  -> shR_bf [32][128]
//   floats [8192,10240)  : hT_out [128][32] bf16 swz  -> shZ_bf [32][128]
//   floats [10240,12288) : Af [2][32][32] fp32        -> vn1/av_/sgp
//   floats [12288,13312) : A_bf [2][32][32] bf16 swz
//   floats [13312,17408) : m_bf [32][256] bf16 swz    -> pbuf [32][128] fp32
// Swizzles: h_bf/m_bf 16B-chunk c at c^(row&7); hT/A_bf 16B-chunk c at
// c^(row&3) (rows are 64B).
// ---------------------------------------------------------------------------
__global__ __launch_bounds__(256, 2) void graph_pipeline(
    const int* __restrict__ x, const int* __restrict__ ei,
    const float* __restrict__ ecount, const float* __restrict__ indeg,
    const float* __restrict__ outdeg, const float* __restrict__ numcount,
    const float* __restrict__ emb,
    const ushort_t* __restrict__ ggT_bf, const float* __restrict__ ggnn_b,
    const ushort_t* __restrict__ wih_bf, const ushort_t* __restrict__ whh_bf,
    const float* __restrict__ bih, const float* __restrict__ bhh,
    const float* __restrict__ W1, const float* __restrict__ W1b,
    const float* __restrict__ W2b,
    const float* __restrict__ qw, const float* __restrict__ qb,
    const float* __restrict__ W3, const float* __restrict__ W3b,
    const ushort_t* __restrict__ w2_bf,
    ushort_t* __restrict__ sh_out)
{
  __shared__ float smemF[17408];  // 69,632 B
  float*    shH    = smemF;                        // [32][128] fp32
  ushort_t* h_bf   = (ushort_t*)(smemF + 4096);    // [32][128] bf16 swz
  ushort_t* hT_in  = (ushort_t*)(smemF + 6144);    // [128][32] bf16 swz
  ushort_t* hT_out = (ushort_t*)(smemF + 8192);
  float*    Af     = smemF + 10240;                // [2][32][32] fp32
  ushort_t* A_bf   = (ushort_t*)(smemF + 12288);   // [2][32][32] bf16 swz
  ushort_t* m_bf   = (ushort_t*)(smemF + 13312);   // [32][256] bf16 swz
  ushort_t* shR_bf = (ushort_t*)(smemF + 6144);    // [32][128] (over hT_in)
  ushort_t* shZ_bf = (ushort_t*)(smemF + 8192);    // (over hT_out)
  float*    vn1    = smemF + 10240;                // (over Af)
  float*    av_    = smemF + 10368;
  float*    sgp    = smemF + 10400;
  float*    pbuf   = smemF + 13312;                // (over m_bf)

  const int t = threadIdx.x;
  const int g = blockIdx.x;

  // ---- edge prefetch (hidden under phase 1a gather) ----
  int es = 0, ed = 0; float wq = 0.f;
  if (t < 128) {
    int e = g * 64 + (t & 63);
    es = ei[e] - g * NPER;
    ed = ei[ETOT + e] - g * NPER;
    float ec = ecount[e];
    wq = ec * ((t < 64) ? indeg[e] : outdeg[e]);
  }

  // ---- phase 1a: gather h = emb[x-1] -> shH fp32 + swizzled h_bf; zero A ----
  #pragma unroll
  for (int c = 0; c < 4; ++c) {
    int idx = c * 256 + t;            // 1024 F4 chunks
    int i = idx >> 5, g4 = idx & 31;
    int row = x[g * NPER + i] - 1;
    F4 v = ld4(emb + (size_t)row * HD + g4 * 4);
    *(F4*)(shH + i * HD + g4 * 4) = v;
    int p = (g4 >> 1) ^ (i & 7);      // 16B-chunk swizzle
    *(us4v*)(h_bf + i * HD + p * 8 + (g4 & 1) * 4) = f2bf4(v);
  }
  { F4 zz = {0.f,0.f,0.f,0.f}; *(F4*)(Af + t * 8) = zz; *(F4*)(Af + t * 8 + 4) = zz; }
  __syncthreads();

  const int lane = t & 63;
  const int w = t >> 6;
  const int q = lane >> 4, lm = lane & 15;

  // ---- phase 1b: A-matrix atomics + GGNN transform -> transposed hT ----
  if (t < 64)       atomicAdd(&Af[ed * 32 + es], wq);
  else if (t < 128) atomicAdd(&Af[1024 + es * 32 + ed], wq);
  {
    const int mat = w >> 1, mt = w & 1;
    bf16x8 hf[4];
    #pragma unroll
    for (int ks = 0; ks < 4; ++ks)
      hf[ks] = ldb8(h_bf + (mt * 16 + lm) * HD + ((ks * 4 + q) ^ (lm & 7)) * 8);
    const ushort_t* Wt = ggT_bf + mat * 16384;   // [j][k]
    const float* bias = ggnn_b + mat * HD;
    ushort_t* dstT = mat ? hT_out : hT_in;
    #pragma unroll
    for (int nt = 0; nt < 8; ++nt) {
      const ushort_t* wp = Wt + (nt * 16 + lm) * HD + q * 8;
      f32x4 acc = {0.f, 0.f, 0.f, 0.f};
      #pragma unroll
      for (int ks = 0; ks < 4; ++ks)
        acc = __builtin_amdgcn_mfma_f32_16x16x32_bf16(hf[ks], ldb8(wp + ks * 32), acc, 0, 0, 0);
      int col = nt * 16 + lm;
      float b = bias[col];
      // hT[col][s], s = mt*16+q*4+r; s-chunk (mt*2+(q>>1)) swz by col&3
      us4v o;
      o.x = f2bf(acc[0] + b); o.y = f2bf(acc[1] + b);
      o.z = f2bf(acc[2] + b); o.w = f2bf(acc[3] + b);
      int chunk = (mt * 2 + (q >> 1)) ^ (col & 3);
      *(us4v*)(dstT + col * 32 + chunk * 8 + (q & 1) * 4) = o;
    }
  }
  __syncthreads();

  // ---- phase 2b: A fp32 -> A_bf swizzled ----
  {
    int dir = t >> 7, d = (t >> 2) & 31, c = t & 3;
    const float* sp = Af + dir * 1024 + d * 32 + c * 8;
    F4 v0 = ld4(sp), v1 = ld4(sp + 4);
    ushort_t* dp = A_bf + dir * 2048 + d * 32 + (c ^ (d & 3)) * 8;
    *(us4v*)dp = f2bf4(v0);
    *(us4v*)(dp + 4) = f2bf4(v1);
  }
  __syncthreads();

  // ---- phase 2c: message GEMM  m = A @ h_{in,out}  -> m_bf swizzled ----
  {
    const int dir = w >> 1, mt = w & 1;
    const ushort_t* Asrc = A_bf + dir * 2048;
    const ushort_t* Hsrc = dir ? hT_out : hT_in;
    bf16x8 afr = ldb8(Asrc + (mt * 16 + lm) * 32 + (q ^ (lm & 3)) * 8);
    #pragma unroll
    for (int nt = 0; nt < 8; ++nt) {
      bf16x8 bfr = ldb8(Hsrc + (nt * 16 + lm) * 32 + (q ^ (lm & 3)) * 8);
      f32x4 acc = {0.f, 0.f, 0.f, 0.f};
      acc = __builtin_amdgcn_mfma_f32_16x16x32_bf16(afr, bfr, acc, 0, 0, 0);
      int col256 = dir * 128 + nt * 16 + lm;
      int c = col256 >> 3;
      #pragma unroll
      for (int r = 0; r < 4; ++r) {
        int row = mt * 16 + q * 4 + r;
        m_bf[row * 256 + (c ^ (row & 7)) * 8 + (col256 & 7)] = f2bf(acc[r]);
      }
    }
  }
  __syncthreads();

  // ---- phase 3: GRU gates via MFMA (R/Z stored bf16) ----
  {
    const int mt = w & 1, jh = w >> 1;
    bf16x8 mf[8], hf4[4];
    #pragma unroll
    for (int ks = 0; ks < 8; ++ks)
      mf[ks] = ldb8(m_bf + (mt * 16 + lm) * 256 + ((ks * 4 + q) ^ (lm & 7)) * 8);
    #pragma unroll
    for (int ks = 0; ks < 4; ++ks)
      hf4[ks] = ldb8(h_bf + (mt * 16 + lm) * HD + ((ks * 4 + q) ^ (lm & 7)) * 8);

#define COMB_TILE(NT) { \
    const int j = (NT) * 16 + lm; \
    const ushort_t* wp = wih_bf + j * 256 + q * 8; \
    const ushort_t* wp2 = whh_bf + j * HD + q * 8; \
    f32x4 acc = {0.f, 0.f, 0.f, 0.f}; \
    _Pragma("unroll") for (int ks = 0; ks < 8; ++ks) \
      acc = __builtin_amdgcn_mfma_f32_16x16x32_bf16(mf[ks], ldb8(wp + ks * 32), acc, 0, 0, 0); \
    _Pragma("unroll") for (int ks = 0; ks < 4; ++ks) \
      acc = __builtin_amdgcn_mfma_f32_16x16x32_bf16(hf4[ks], ldb8(wp2 + ks * 32), acc, 0, 0, 0); \
    const float bsum = bih[j] + bhh[j]; \
    ushort_t* dstp = (j < HD) ? (shR_bf + (mt * 16 + q * 4) * HD + j) \
                              : (shZ_bf + (mt * 16 + q * 4) * HD + j - HD); \
    _Pragma("unroll") for (int r = 0; r < 4; ++r) dstp[r * HD] = f2bf(sigm(acc[r] + bsum)); \
  }
    if (jh == 0) {
      #pragma unroll
      for (int c = 0; c < 12; ++c) COMB_TILE(c)
    } else {
      #pragma unroll
      for (int c = 12; c < 16; ++c) COMB_TILE(c)
    }
#undef COMB_TILE
    __syncthreads();   // shR/shZ complete (uniform barrier)

    if (jh == 1) {     // n-gate tiles + h' update + h'_bf (waves 2,3)
      #pragma unroll
      for (int c = 0; c < 8; ++c) {
        const int j = 256 + c * 16 + lm;
        const int jc2 = c * 16 + lm;
        const ushort_t* wp = wih_bf + j * 256 + q * 8;
        const ushort_t* wp2 = whh_bf + j * HD + q * 8;
        f32x4 aa = {0.f, 0.f, 0.f, 0.f}, ag = {0.f, 0.f, 0.f, 0.f};
        #pragma unroll
        for (int ks = 0; ks < 8; ++ks)
          aa = __builtin_amdgcn_mfma_f32_16x16x32_bf16(mf[ks], ldb8(wp + ks * 32), aa, 0, 0, 0);
        #pragma unroll
        for (int ks = 0; ks < 4; ++ks)
          ag = __builtin_amdgcn_mfma_f32_16x16x32_bf16(hf4[ks], ldb8(wp2 + ks * 32), ag, 0, 0, 0);
        const float ba = bih[j], bg = bhh[j];
        #pragma unroll
        for (int r = 0; r < 4; ++r) {
          const int row = mt * 16 + q * 4 + r;
          float rv = bf2f(shR_bf[row * HD + jc2]);
          float nn = tanh_fast(aa[r] + ba + rv * (ag[r] + bg));
          float zv = bf2f(shZ_bf[row * HD + jc2]);
          float hold = shH[row * HD + jc2];
          float hnew = (1.f - zv) * nn + zv * hold;
          shH[row * HD + jc2] = hnew;
          h_bf[row * HD + (((jc2 >> 3)) ^ (row & 7)) * 8 + (jc2 & 7)] = f2bf(hnew);
        }
      }
    }
  }
  __syncthreads();

  // ---- phase 5a: vn1[j] = v_n@W1^T[j] + W1b[j] + W2b[j]  (v_n = h'[31]) ----
  if (t < 128) {
    const int j = t;
    float acc = W1b[j] + W2b[j];
    const float* Wr = W1 + j * HD;
    for (int kt = 0; kt < 32; ++kt) {
      F4 w_ = ld4(Wr + kt * 4);
      F4 hv = ld4(shH + 31 * HD + kt * 4);
      acc += w_.x * hv.x + w_.y * hv.y + w_.z * hv.z + w_.w * hv.w;
    }
    vn1[j] = acc;
  }
  __syncthreads();

  // ---- phase 5b: p = sigmoid(vn1 + h'@W2^T) via MFMA -> pbuf fp32 ----
  {
    const int mt = w & 1;
    bf16x8 hpf[4];
    #pragma unroll
    for (int ks = 0; ks < 4; ++ks)
      hpf[ks] = ldb8(h_bf + (mt * 16 + lm) * HD + ((ks * 4 + q) ^ (lm & 7)) * 8);
    #pragma unroll
    for (int c = 0; c < 4; ++c) {
      const int nt = (w >> 1) * 4 + c;
      const ushort_t* wp = w2_bf + (nt * 16 + lm) * HD + q * 8;
      f32x4 acc = {0.f, 0.f, 0.f, 0.f};
      #pragma unroll
      for (int ks = 0; ks < 4; ++ks)
        acc = __builtin_amdgcn_mfma_f32_16x16x32_bf16(hpf[ks], ldb8(wp + ks * 32), acc, 0, 0, 0);
      const int col = nt * 16 + lm;
      float v1 = vn1[col];
      #pragma unroll
      for (int r = 0; r < 4; ++r)
        pbuf[(mt * 16 + q * 4 + r) * HD + col] = sigm(acc[r] + v1);
    }
  }
  __syncthreads();

  // ---- phase 5c: alpha[i] = p[i,:]@qw + qb; av = alpha*num_count ----
  {
    const int wv = t >> 6, l = t & 63;
    float q0 = qw[l], q1 = qw[64 + l];
    float qbv = qb[0];
    for (int r = 0; r < 8; ++r) {
      int i = wv * 8 + r;
      float v = pbuf[i * HD + l] * q0 + pbuf[i * HD + 64 + l] * q1;
      v += __shfl_down(v, 32);
      v += __shfl_down(v, 16);
      v += __shfl_down(v, 8);
      v += __shfl_down(v, 4);
      v += __shfl_down(v, 2);
      v += __shfl_down(v, 1);
      if (l == 0) av_[i] = (v + qbv) * numcount[g * NPER + i];
    }
  }
  __syncthreads();

  // ---- phase 5d: s_g[j] = sum_i av[i]*h'[i][j] (two halves) ----
  const int jc = t & 127;
  {
    const int ih = t >> 7;
    float acc = 0.f;
    #pragma unroll
    for (int i = 0; i < 16; ++i) {
      int ii = ih * 16 + i;
      acc += av_[ii] * shH[ii * HD + jc];
    }
    sgp[ih * HD + jc] = acc;
  }
  __syncthreads();

  // ---- phase 5e: s_h[j] = [v_n, s_g]@W3^T[j] + W3b[j], store bf16 ----
  if (t < 128) {
    const int j = t;
    float acc = W3b[j];
    const float* Wr = W3 + j * 256;
    for (int kt = 0; kt < 32; ++kt) {
      F4 w_ = ld4(Wr + kt * 4);
      F4 hv = ld4(shH + 31 * HD + kt * 4);
      acc += w_.x * hv.x + w_.y * hv.y + w_.z * hv.z + w_.w * hv.w;
      F4 w2 = ld4(Wr + 128 + kt * 4);
      F4 s0 = ld4(sgp + kt * 4);
      F4 s1 = ld4(sgp + 128 + kt * 4);
      acc += w2.x * (s0.x + s1.x) + w2.y * (s0.y + s1.y) +
             w2.z * (s0.z + s1.z) + w2.w * (s0.w + s1.w);
    }
    sh_out[g * HD + j] = f2bf(acc);
  }
}

// ---------------------------------------------------------------------------
// final_gemm v3: out[1024][100000] = s_h(bf16) @ emb_bf^T, fp32 out.
// Barrier-free streaming: no LDS. Block = 64-row m-tile (4 waves x 16 rows),
// loops 4 n-tiles (stride 196). A-frags in regs; B-frags direct from global
// (L1/L2-resident, emb_bf = 25.6MB); accumulators stored directly with
// non-temporal dword stores (64B-contiguous per 16-lane group).
// ---------------------------------------------------------------------------
__global__ __launch_bounds__(256, 4) void final_gemm(
    const ushort_t* __restrict__ A, const ushort_t* __restrict__ Bb,
    float* __restrict__ out)
{
  const int t = threadIdx.x;
  const int lane = t & 63, w = t >> 6;
  const int q = lane >> 4, lm = lane & 15;
  const int m0 = blockIdx.x * 64;
  const int by = blockIdx.y;

  bf16x8 af[4];
  #pragma unroll
  for (int kc = 0; kc < 4; ++kc)
    af[kc] = ldb8(A + (size_t)(m0 + w * 16 + lm) * HD + kc * 32 + q * 8);

  const size_t orow = (size_t)(m0 + w * 16 + q * 4) * NNODE_V;

  for (int it = 0; it < 4; ++it) {
    int tile = by + 196 * it;
    if (tile >= 782) break;                 // 782 tiles cover 100,096 >= 100,000
    int n0 = tile * 128;
    #pragma unroll
    for (int tg = 0; tg < 8; ++tg) {
      int gr = n0 + tg * 16 + lm;
      int grc = gr < NNODE_V ? gr : NNODE_V - 1;
      const ushort_t* bp = Bb + (size_t)grc * HD + q * 8;
      f32x4 a_ = {0.f, 0.f, 0.f, 0.f};
      #pragma unroll
      for (int kc = 0; kc < 4; ++kc)
        a_ = __builtin_amdgcn_mfma_f32_16x16x32_bf16(af[kc], ldb8(bp + kc * 32), a_, 0, 0, 0);
      if (gr < NNODE_V) {
        float* op = out + orow + gr;
        #pragma unroll
        for (int r = 0; r < 4; ++r)
          __builtin_nontemporal_store(a_[r], op + (size_t)r * NNODE_V);
      }
    }
  }
}

// ---------------------------------------------------------------------------
extern "C" void kernel_launch(void* const* d_in, const int* in_sizes, int n_in,
                              void* d_out, int out_size, void* d_ws, size_t ws_size,
                              hipStream_t stream) {
  (void)in_sizes; (void)n_in; (void)out_size; (void)ws_size;
  const int*   x        = (const int*)d_in[0];
  const int*   ei       = (const int*)d_in[1];
  const float* ecount   = (const float*)d_in[3];
  const float* indeg    = (const float*)d_in[4];
  const float* outdeg   = (const float*)d_in[5];
  const float* numcount = (const float*)d_in[6];
  const float* emb      = (const float*)d_in[8];
  const float* ggnn_w   = (const float*)d_in[9];
  const float* ggnn_b   = (const float*)d_in[10];
  const float* wih      = (const float*)d_in[11];
  const float* whh      = (const float*)d_in[12];
  const float* bih      = (const float*)d_in[13];
  const float* bhh      = (const float*)d_in[14];
  const float* W1       = (const float*)d_in[15];
  const float* W1b      = (const float*)d_in[16];
  const float* W2       = (const float*)d_in[17];
  const float* W2b      = (const float*)d_in[18];
  const float* qw       = (const float*)d_in[19];
  const float* qb       = (const float*)d_in[20];
  const float* W3       = (const float*)d_in[21];
  const float* W3b      = (const float*)d_in[22];
  float*       out      = (float*)d_out;

  char* ws = (char*)d_ws;
  ushort_t* emb_bf = (ushort_t*)(ws + WS_EMB_OFF);
  ushort_t* sh_ws  = (ushort_t*)(ws + WS_SH_OFF);
  ushort_t* wih_bf = (ushort_t*)(ws + WS_WIH_OFF);
  ushort_t* whh_bf = (ushort_t*)(ws + WS_WHH_OFF);
  ushort_t* ggT_bf = (ushort_t*)(ws + WS_GGT_OFF);
  ushort_t* w2_bf  = (ushort_t*)(ws + WS_W2T_OFF);

  prep_all<<<dim3(6346), dim3(256), 0, stream>>>(
      emb, emb_bf, wih, whh, ggnn_w, W2, wih_bf, whh_bf, ggT_bf, w2_bf);

  graph_pipeline<<<dim3(NGRAPH), dim3(256), 0, stream>>>(
      x, ei, ecount, indeg, outdeg, numcount, emb, ggT_bf, ggnn_b,
      wih_bf, whh_bf, bih, bhh, W1, W1b, W2b, qw, qb, W3, W3b, w2_bf, sh_ws);

  final_gemm<<<dim3(16, 196), dim3(256), 0, stream>>>(sh_ws, emb_bf, out);
}

// Round 3
// 615.832 us; speedup vs baseline: 1.1816x; 1.1816x over previous
//
#include <hip/hip_runtime.h>

// ---------------------------------------------------------------------------
// SR-GNN fused implementation for MI355X / gfx950 — round 4.
//
// r3 result: 727.6us (regression vs r2's 658). Suspect: final_gemm v3's
// scattered global B-frag loads (16x64B segments/instr, 4x wave redundancy)
// + nontemporal dword stores. Also found+fixed a latent LDS race in
// graph_pipeline (A_bf offset in shorts, not bytes: dir*2048 -> dir*1024).
//
// r4 design:
//  - graph_pipeline v4.1: race fix only.
//  - final_gemm v4: one n-tile per block, B staged once into XOR-swizzled
//    LDS (2-way conflicts ~free vs v2's 8-way with pad-136), ONE barrier per
//    block; loop 8 m-tiles; wave-private LDS transpose buffers (barrier-free)
//    for fully-coalesced dwordx4 stores; plain stores through L2.
//    LDS 66.5KB -> 2 blocks/CU. Grid (2,782).
// ---------------------------------------------------------------------------

typedef unsigned short ushort_t;
typedef __attribute__((ext_vector_type(8))) short bf16x8;     // 8 bf16 (4 VGPR)
typedef __attribute__((ext_vector_type(4))) float f32x4;
typedef __attribute__((ext_vector_type(4))) ushort_t us4v;    // 8 B
typedef __attribute__((ext_vector_type(8))) ushort_t us8v;    // 16 B

#define HD 128
#define NPER 32
#define NGRAPH 1024
#define NNODE_V 100000
#define ETOT 65536

struct F4 { float x, y, z, w; };

__device__ __forceinline__ F4 ld4(const float* p) { return *(const F4*)p; }
__device__ __forceinline__ bf16x8 ldb8(const ushort_t* p) { return *(const bf16x8*)p; }

__device__ __forceinline__ float sigm(float x) { return 1.0f / (1.0f + __expf(-x)); }

__device__ __forceinline__ float tanh_fast(float x) {
  float ax = fabsf(x);
  float t = __expf(-2.0f * ax);
  float r = (1.0f - t) / (1.0f + t);
  return copysignf(r, x);
}

__device__ __forceinline__ ushort_t f2bf(float f) {  // RNE fp32 -> bf16
  unsigned u = __float_as_uint(f);
  u = u + 0x7FFFu + ((u >> 16) & 1u);
  return (ushort_t)(u >> 16);
}
__device__ __forceinline__ float bf2f(ushort_t b) {
  return __uint_as_float(((unsigned)b) << 16);
}
__device__ __forceinline__ us4v f2bf4(F4 v) {
  us4v o; o.x = f2bf(v.x); o.y = f2bf(v.y); o.z = f2bf(v.z); o.w = f2bf(v.w);
  return o;
}

// ---------------------------------------------------------------------------
// ws layout (bytes):
//   emb_bf  @ 0           : 100000*128*2 = 25,600,000
//   s_h     @ 25,600,000  : 1024*128*2   =    262,144
//   wih_bf  @ 25,862,144  : 384*256*2    =    196,608
//   whh_bf  @ 26,058,752  : 384*128*2    =     98,304
//   ggT_bf  @ 26,157,056  : 2*128*128*2  =     65,536   ([mat][j][k])
//   w2_bf   @ 26,222,592  : 128*128*2    =     32,768   ([j][k])
// ---------------------------------------------------------------------------
#define WS_EMB_OFF   0
#define WS_SH_OFF    25600000
#define WS_WIH_OFF   25862144
#define WS_WHH_OFF   26058752
#define WS_GGT_OFF   26157056
#define WS_W2T_OFF   26222592

// ---------------------------------------------------------------------------
// prep_all: blocks [0,6250) convert emb; blocks [6250,6346) convert weights.
// ---------------------------------------------------------------------------
__global__ void prep_all(const float* __restrict__ emb, ushort_t* __restrict__ emb_bf,
                         const float* __restrict__ wih, const float* __restrict__ whh,
                         const float* __restrict__ ggnn_w, const float* __restrict__ W2,
                         ushort_t* __restrict__ wih_bf, ushort_t* __restrict__ whh_bf,
                         ushort_t* __restrict__ ggT_bf, ushort_t* __restrict__ w2_bf) {
  const int b = blockIdx.x, t = threadIdx.x;
  if (b < 6250) {
    int tid = b * 256 + t;                  // 1.6M threads x 8 floats
    const float* s = emb + (size_t)tid * 8;
    F4 v0 = ld4(s), v1 = ld4(s + 4);
    us8v o;
    o.s0 = f2bf(v0.x); o.s1 = f2bf(v0.y); o.s2 = f2bf(v0.z); o.s3 = f2bf(v0.w);
    o.s4 = f2bf(v1.x); o.s5 = f2bf(v1.y); o.s6 = f2bf(v1.z); o.s7 = f2bf(v1.w);
    *(us8v*)(emb_bf + (size_t)tid * 8) = o;
    return;
  }
  int tid = (b - 6250) * 256 + t;           // 96*256 = 24576
  { F4 v = ld4(wih + tid * 4); *(us4v*)(wih_bf + tid * 4) = f2bf4(v); }
  if (tid < 12288) { F4 v = ld4(whh + tid * 4); *(us4v*)(whh_bf + tid * 4) = f2bf4(v); }
  if (tid < 16384) {                        // ggnn_w [mat][k][j] -> [mat][j][k]
    int o = tid * 2;
    int mat = o >> 14, r = o & 16383, j = r >> 7, k = r & 127;
    float v0 = ggnn_w[mat * 16384 + k * 128 + j];
    float v1 = ggnn_w[mat * 16384 + (k + 1) * 128 + j];
    unsigned pk = (unsigned)f2bf(v0) | ((unsigned)f2bf(v1) << 16);
    *(unsigned*)(ggT_bf + o) = pk;
  }
  if (tid < 4096) {                         // W2 already [j][k]
    F4 v = ld4(W2 + tid * 4); *(us4v*)(w2_bf + tid * 4) = f2bf4(v);
  }
}

// ---------------------------------------------------------------------------
// graph_pipeline v4.1: one block per graph.  LDS 69,632B (2 blocks/CU).
//   floats [0,4096)      : shH [32][128] fp32 (h, updated in place)
//   floats [4096,6144)   : h_bf [32][128] bf16 swz (pre-GRU h; phase4: h')
//   floats [6144,8192)   : hT_in  [128][32] bf16 swz  -> shR_bf [32][128]
//   floats [8192,10240)  : hT_out [128][32] bf16 swz  -> shZ_bf [32][128]
//   floats [10240,12288) : Af [2][32][32] fp32        -> vn1/av_/sgp
//   floats [12288,13312) : A_bf [2][32][32] bf16 swz  (dir stride 1024 shorts)
//   floats [13312,17408) : m_bf [32][256] bf16 swz    -> pbuf [32][128] fp32
// ---------------------------------------------------------------------------
__global__ __launch_bounds__(256, 2) void graph_pipeline(
    const int* __restrict__ x, const int* __restrict__ ei,
    const float* __restrict__ ecount, const float* __restrict__ indeg,
    const float* __restrict__ outdeg, const float* __restrict__ numcount,
    const float* __restrict__ emb,
    const ushort_t* __restrict__ ggT_bf, const float* __restrict__ ggnn_b,
    const ushort_t* __restrict__ wih_bf, const ushort_t* __restrict__ whh_bf,
    const float* __restrict__ bih, const float* __restrict__ bhh,
    const float* __restrict__ W1, const float* __restrict__ W1b,
    const float* __restrict__ W2b,
    const float* __restrict__ qw, const float* __restrict__ qb,
    const float* __restrict__ W3, const float* __restrict__ W3b,
    const ushort_t* __restrict__ w2_bf,
    ushort_t* __restrict__ sh_out)
{
  __shared__ float smemF[17408];  // 69,632 B
  float*    shH    = smemF;                        // [32][128] fp32
  ushort_t* h_bf   = (ushort_t*)(smemF + 4096);    // [32][128] bf16 swz
  ushort_t* hT_in  = (ushort_t*)(smemF + 6144);    // [128][32] bf16 swz
  ushort_t* hT_out = (ushort_t*)(smemF + 8192);
  float*    Af     = smemF + 10240;                // [2][32][32] fp32
  ushort_t* A_bf   = (ushort_t*)(smemF + 12288);   // [2][32][32] bf16 swz
  ushort_t* m_bf   = (ushort_t*)(smemF + 13312);   // [32][256] bf16 swz
  ushort_t* shR_bf = (ushort_t*)(smemF + 6144);    // [32][128] (over hT_in)
  ushort_t* shZ_bf = (ushort_t*)(smemF + 8192);    // (over hT_out)
  float*    vn1    = smemF + 10240;                // (over Af)
  float*    av_    = smemF + 10368;
  float*    sgp    = smemF + 10400;
  float*    pbuf   = smemF + 13312;                // (over m_bf)

  const int t = threadIdx.x;
  const int g = blockIdx.x;

  // ---- edge prefetch (hidden under phase 1a gather) ----
  int es = 0, ed = 0; float wq = 0.f;
  if (t < 128) {
    int e = g * 64 + (t & 63);
    es = ei[e] - g * NPER;
    ed = ei[ETOT + e] - g * NPER;
    float ec = ecount[e];
    wq = ec * ((t < 64) ? indeg[e] : outdeg[e]);
  }

  // ---- phase 1a: gather h = emb[x-1] -> shH fp32 + swizzled h_bf; zero A ----
  #pragma unroll
  for (int c = 0; c < 4; ++c) {
    int idx = c * 256 + t;            // 1024 F4 chunks
    int i = idx >> 5, g4 = idx & 31;
    int row = x[g * NPER + i] - 1;
    F4 v = ld4(emb + (size_t)row * HD + g4 * 4);
    *(F4*)(shH + i * HD + g4 * 4) = v;
    int p = (g4 >> 1) ^ (i & 7);      // 16B-chunk swizzle
    *(us4v*)(h_bf + i * HD + p * 8 + (g4 & 1) * 4) = f2bf4(v);
  }
  { F4 zz = {0.f,0.f,0.f,0.f}; *(F4*)(Af + t * 8) = zz; *(F4*)(Af + t * 8 + 4) = zz; }
  __syncthreads();

  const int lane = t & 63;
  const int w = t >> 6;
  const int q = lane >> 4, lm = lane & 15;

  // ---- phase 1b: A-matrix atomics + GGNN transform -> transposed hT ----
  if (t < 64)       atomicAdd(&Af[ed * 32 + es], wq);
  else if (t < 128) atomicAdd(&Af[1024 + es * 32 + ed], wq);
  {
    const int mat = w >> 1, mt = w & 1;
    bf16x8 hf[4];
    #pragma unroll
    for (int ks = 0; ks < 4; ++ks)
      hf[ks] = ldb8(h_bf + (mt * 16 + lm) * HD + ((ks * 4 + q) ^ (lm & 7)) * 8);
    const ushort_t* Wt = ggT_bf + mat * 16384;   // [j][k]
    const float* bias = ggnn_b + mat * HD;
    ushort_t* dstT = mat ? hT_out : hT_in;
    #pragma unroll
    for (int nt = 0; nt < 8; ++nt) {
      const ushort_t* wp = Wt + (nt * 16 + lm) * HD + q * 8;
      f32x4 acc = {0.f, 0.f, 0.f, 0.f};
      #pragma unroll
      for (int ks = 0; ks < 4; ++ks)
        acc = __builtin_amdgcn_mfma_f32_16x16x32_bf16(hf[ks], ldb8(wp + ks * 32), acc, 0, 0, 0);
      int col = nt * 16 + lm;
      float b = bias[col];
      // hT[col][s], s = mt*16+q*4+r; s-chunk (mt*2+(q>>1)) swz by col&3
      us4v o;
      o.x = f2bf(acc[0] + b); o.y = f2bf(acc[1] + b);
      o.z = f2bf(acc[2] + b); o.w = f2bf(acc[3] + b);
      int chunk = (mt * 2 + (q >> 1)) ^ (col & 3);
      *(us4v*)(dstT + col * 32 + chunk * 8 + (q & 1) * 4) = o;
    }
  }
  __syncthreads();

  // ---- phase 2b: A fp32 -> A_bf swizzled (dir stride 1024 shorts) ----
  {
    int dir = t >> 7, d = (t >> 2) & 31, c = t & 3;
    const float* sp = Af + dir * 1024 + d * 32 + c * 8;
    F4 v0 = ld4(sp), v1 = ld4(sp + 4);
    ushort_t* dp = A_bf + dir * 1024 + d * 32 + (c ^ (d & 3)) * 8;
    *(us4v*)dp = f2bf4(v0);
    *(us4v*)(dp + 4) = f2bf4(v1);
  }
  __syncthreads();

  // ---- phase 2c: message GEMM  m = A @ h_{in,out}  -> m_bf swizzled ----
  {
    const int dir = w >> 1, mt = w & 1;
    const ushort_t* Asrc = A_bf + dir * 1024;
    const ushort_t* Hsrc = dir ? hT_out : hT_in;
    bf16x8 afr = ldb8(Asrc + (mt * 16 + lm) * 32 + (q ^ (lm & 3)) * 8);
    #pragma unroll
    for (int nt = 0; nt < 8; ++nt) {
      bf16x8 bfr = ldb8(Hsrc + (nt * 16 + lm) * 32 + (q ^ (lm & 3)) * 8);
      f32x4 acc = {0.f, 0.f, 0.f, 0.f};
      acc = __builtin_amdgcn_mfma_f32_16x16x32_bf16(afr, bfr, acc, 0, 0, 0);
      int col256 = dir * 128 + nt * 16 + lm;
      int c = col256 >> 3;
      #pragma unroll
      for (int r = 0; r < 4; ++r) {
        int row = mt * 16 + q * 4 + r;
        m_bf[row * 256 + (c ^ (row & 7)) * 8 + (col256 & 7)] = f2bf(acc[r]);
      }
    }
  }
  __syncthreads();

  // ---- phase 3: GRU gates via MFMA (R/Z stored bf16) ----
  {
    const int mt = w & 1, jh = w >> 1;
    bf16x8 mf[8], hf4[4];
    #pragma unroll
    for (int ks = 0; ks < 8; ++ks)
      mf[ks] = ldb8(m_bf + (mt * 16 + lm) * 256 + ((ks * 4 + q) ^ (lm & 7)) * 8);
    #pragma unroll
    for (int ks = 0; ks < 4; ++ks)
      hf4[ks] = ldb8(h_bf + (mt * 16 + lm) * HD + ((ks * 4 + q) ^ (lm & 7)) * 8);

#define COMB_TILE(NT) { \
    const int j = (NT) * 16 + lm; \
    const ushort_t* wp = wih_bf + j * 256 + q * 8; \
    const ushort_t* wp2 = whh_bf + j * HD + q * 8; \
    f32x4 acc = {0.f, 0.f, 0.f, 0.f}; \
    _Pragma("unroll") for (int ks = 0; ks < 8; ++ks) \
      acc = __builtin_amdgcn_mfma_f32_16x16x32_bf16(mf[ks], ldb8(wp + ks * 32), acc, 0, 0, 0); \
    _Pragma("unroll") for (int ks = 0; ks < 4; ++ks) \
      acc = __builtin_amdgcn_mfma_f32_16x16x32_bf16(hf4[ks], ldb8(wp2 + ks * 32), acc, 0, 0, 0); \
    const float bsum = bih[j] + bhh[j]; \
    ushort_t* dstp = (j < HD) ? (shR_bf + (mt * 16 + q * 4) * HD + j) \
                              : (shZ_bf + (mt * 16 + q * 4) * HD + j - HD); \
    _Pragma("unroll") for (int r = 0; r < 4; ++r) dstp[r * HD] = f2bf(sigm(acc[r] + bsum)); \
  }
    if (jh == 0) {
      #pragma unroll
      for (int c = 0; c < 12; ++c) COMB_TILE(c)
    } else {
      #pragma unroll
      for (int c = 12; c < 16; ++c) COMB_TILE(c)
    }
#undef COMB_TILE
    __syncthreads();   // shR/shZ complete (uniform barrier)

    if (jh == 1) {     // n-gate tiles + h' update + h'_bf (waves 2,3)
      #pragma unroll
      for (int c = 0; c < 8; ++c) {
        const int j = 256 + c * 16 + lm;
        const int jc2 = c * 16 + lm;
        const ushort_t* wp = wih_bf + j * 256 + q * 8;
        const ushort_t* wp2 = whh_bf + j * HD + q * 8;
        f32x4 aa = {0.f, 0.f, 0.f, 0.f}, ag = {0.f, 0.f, 0.f, 0.f};
        #pragma unroll
        for (int ks = 0; ks < 8; ++ks)
          aa = __builtin_amdgcn_mfma_f32_16x16x32_bf16(mf[ks], ldb8(wp + ks * 32), aa, 0, 0, 0);
        #pragma unroll
        for (int ks = 0; ks < 4; ++ks)
          ag = __builtin_amdgcn_mfma_f32_16x16x32_bf16(hf4[ks], ldb8(wp2 + ks * 32), ag, 0, 0, 0);
        const float ba = bih[j], bg = bhh[j];
        #pragma unroll
        for (int r = 0; r < 4; ++r) {
          const int row = mt * 16 + q * 4 + r;
          float rv = bf2f(shR_bf[row * HD + jc2]);
          float nn = tanh_fast(aa[r] + ba + rv * (ag[r] + bg));
          float zv = bf2f(shZ_bf[row * HD + jc2]);
          float hold = shH[row * HD + jc2];
          float hnew = (1.f - zv) * nn + zv * hold;
          shH[row * HD + jc2] = hnew;
          h_bf[row * HD + (((jc2 >> 3)) ^ (row & 7)) * 8 + (jc2 & 7)] = f2bf(hnew);
        }
      }
    }
  }
  __syncthreads();

  // ---- phase 5a: vn1[j] = v_n@W1^T[j] + W1b[j] + W2b[j]  (v_n = h'[31]) ----
  if (t < 128) {
    const int j = t;
    float acc = W1b[j] + W2b[j];
    const float* Wr = W1 + j * HD;
    for (int kt = 0; kt < 32; ++kt) {
      F4 w_ = ld4(Wr + kt * 4);
      F4 hv = ld4(shH + 31 * HD + kt * 4);
      acc += w_.x * hv.x + w_.y * hv.y + w_.z * hv.z + w_.w * hv.w;
    }
    vn1[j] = acc;
  }
  __syncthreads();

  // ---- phase 5b: p = sigmoid(vn1 + h'@W2^T) via MFMA -> pbuf fp32 ----
  {
    const int mt = w & 1;
    bf16x8 hpf[4];
    #pragma unroll
    for (int ks = 0; ks < 4; ++ks)
      hpf[ks] = ldb8(h_bf + (mt * 16 + lm) * HD + ((ks * 4 + q) ^ (lm & 7)) * 8);
    #pragma unroll
    for (int c = 0; c < 4; ++c) {
      const int nt = (w >> 1) * 4 + c;
      const ushort_t* wp = w2_bf + (nt * 16 + lm) * HD + q * 8;
      f32x4 acc = {0.f, 0.f, 0.f, 0.f};
      #pragma unroll
      for (int ks = 0; ks < 4; ++ks)
        acc = __builtin_amdgcn_mfma_f32_16x16x32_bf16(hpf[ks], ldb8(wp + ks * 32), acc, 0, 0, 0);
      const int col = nt * 16 + lm;
      float v1 = vn1[col];
      #pragma unroll
      for (int r = 0; r < 4; ++r)
        pbuf[(mt * 16 + q * 4 + r) * HD + col] = sigm(acc[r] + v1);
    }
  }
  __syncthreads();

  // ---- phase 5c: alpha[i] = p[i,:]@qw + qb; av = alpha*num_count ----
  {
    const int wv = t >> 6, l = t & 63;
    float q0 = qw[l], q1 = qw[64 + l];
    float qbv = qb[0];
    for (int r = 0; r < 8; ++r) {
      int i = wv * 8 + r;
      float v = pbuf[i * HD + l] * q0 + pbuf[i * HD + 64 + l] * q1;
      v += __shfl_down(v, 32);
      v += __shfl_down(v, 16);
      v += __shfl_down(v, 8);
      v += __shfl_down(v, 4);
      v += __shfl_down(v, 2);
      v += __shfl_down(v, 1);
      if (l == 0) av_[i] = (v + qbv) * numcount[g * NPER + i];
    }
  }
  __syncthreads();

  // ---- phase 5d: s_g[j] = sum_i av[i]*h'[i][j] (two halves) ----
  const int jc = t & 127;
  {
    const int ih = t >> 7;
    float acc = 0.f;
    #pragma unroll
    for (int i = 0; i < 16; ++i) {
      int ii = ih * 16 + i;
      acc += av_[ii] * shH[ii * HD + jc];
    }
    sgp[ih * HD + jc] = acc;
  }
  __syncthreads();

  // ---- phase 5e: s_h[j] = [v_n, s_g]@W3^T[j] + W3b[j], store bf16 ----
  if (t < 128) {
    const int j = t;
    float acc = W3b[j];
    const float* Wr = W3 + j * 256;
    for (int kt = 0; kt < 32; ++kt) {
      F4 w_ = ld4(Wr + kt * 4);
      F4 hv = ld4(shH + 31 * HD + kt * 4);
      acc += w_.x * hv.x + w_.y * hv.y + w_.z * hv.z + w_.w * hv.w;
      F4 w2 = ld4(Wr + 128 + kt * 4);
      F4 s0 = ld4(sgp + kt * 4);
      F4 s1 = ld4(sgp + 128 + kt * 4);
      acc += w2.x * (s0.x + s1.x) + w2.y * (s0.y + s1.y) +
             w2.z * (s0.z + s1.z) + w2.w * (s0.w + s1.w);
    }
    sh_out[g * HD + j] = f2bf(acc);
  }
}

// ---------------------------------------------------------------------------
// final_gemm v4: out[1024][100000] = s_h(bf16) @ emb_bf^T, fp32 out.
// One n-tile (128 vocab rows) per block, staged once into XOR-swizzled LDS
// (read conflicts 2-way ~ free); ONE barrier per block. Each block computes
// 512 m-rows (grid (2,782)); per wave: 8 m-tiles of 16 rows. Wave-private
// LDS transpose buffer (no barriers) -> fully-coalesced dwordx4 stores.
// LDS = 32,768 (Bsh) + 33,792 (Tsh) = 66,560B -> 2 blocks/CU.
// ---------------------------------------------------------------------------
__global__ __launch_bounds__(256, 2) void final_gemm(
    const ushort_t* __restrict__ A, const ushort_t* __restrict__ Bb,
    float* __restrict__ out)
{
  __shared__ ushort_t Bsh[128 * 128];     // 32,768B  swizzled: chunk ch^(row&7)
  __shared__ float    Tsh[4][16 * 132];   // 33,792B  wave-private transpose
  const int t = threadIdx.x;
  const int lane = t & 63, w = t >> 6;
  const int q = lane >> 4, lm = lane & 15;
  const int n0 = blockIdx.y * 128;
  const int mbase = blockIdx.x * 512 + w * 128;

  // stage B: 8 passes x 256 threads x 16B chunks (coalesced global reads)
  #pragma unroll
  for (int p = 0; p < 8; ++p) {
    int c = p * 256 + t;
    int row = c >> 4, ch = c & 15;
    int gr = n0 + row; if (gr >= NNODE_V) gr = NNODE_V - 1;
    *(us8v*)(Bsh + row * 128 + (ch ^ (row & 7)) * 8) =
        *(const us8v*)(Bb + (size_t)gr * HD + ch * 8);
  }
  __syncthreads();

  float* T = Tsh[w];
  for (int mt = 0; mt < 8; ++mt) {
    const int mrow = mbase + mt * 16;
    bf16x8 af[4];
    #pragma unroll
    for (int kc = 0; kc < 4; ++kc)
      af[kc] = ldb8(A + (size_t)(mrow + lm) * HD + kc * 32 + q * 8);

    #pragma unroll
    for (int tg = 0; tg < 8; ++tg) {
      const ushort_t* bp = Bsh + (tg * 16 + lm) * 128;
      f32x4 acc = {0.f, 0.f, 0.f, 0.f};
      #pragma unroll
      for (int kc = 0; kc < 4; ++kc)
        acc = __builtin_amdgcn_mfma_f32_16x16x32_bf16(
            af[kc], ldb8(bp + ((kc * 4 + q) ^ (lm & 7)) * 8), acc, 0, 0, 0);
      #pragma unroll
      for (int r = 0; r < 4; ++r)
        T[(q * 4 + r) * 132 + tg * 16 + lm] = acc[r];
    }
    // wave-private transpose read + coalesced store (no cross-wave hazard;
    // compiler inserts lgkmcnt for the write->read dependence)
    #pragma unroll
    for (int p = 0; p < 8; ++p) {
      int r2 = p * 2 + (lane >> 5);
      int cq = (lane & 31) * 4;
      if (n0 + cq + 4 <= NNODE_V) {
        F4 v = *(const F4*)(T + r2 * 132 + cq);
        *(F4*)(out + (size_t)(mrow + r2) * NNODE_V + n0 + cq) = v;
      }
    }
  }
}

// ---------------------------------------------------------------------------
extern "C" void kernel_launch(void* const* d_in, const int* in_sizes, int n_in,
                              void* d_out, int out_size, void* d_ws, size_t ws_size,
                              hipStream_t stream) {
  (void)in_sizes; (void)n_in; (void)out_size; (void)ws_size;
  const int*   x        = (const int*)d_in[0];
  const int*   ei       = (const int*)d_in[1];
  const float* ecount   = (const float*)d_in[3];
  const float* indeg    = (const float*)d_in[4];
  const float* outdeg   = (const float*)d_in[5];
  const float* numcount = (const float*)d_in[6];
  const float* emb      = (const float*)d_in[8];
  const float* ggnn_w   = (const float*)d_in[9];
  const float* ggnn_b   = (const float*)d_in[10];
  const float* wih      = (const float*)d_in[11];
  const float* whh      = (const float*)d_in[12];
  const float* bih      = (const float*)d_in[13];
  const float* bhh      = (const float*)d_in[14];
  const float* W1       = (const float*)d_in[15];
  const float* W1b      = (const float*)d_in[16];
  const float* W2       = (const float*)d_in[17];
  const float* W2b      = (const float*)d_in[18];
  const float* qw       = (const float*)d_in[19];
  const float* qb       = (const float*)d_in[20];
  const float* W3       = (const float*)d_in[21];
  const float* W3b      = (const float*)d_in[22];
  float*       out      = (float*)d_out;

  char* ws = (char*)d_ws;
  ushort_t* emb_bf = (ushort_t*)(ws + WS_EMB_OFF);
  ushort_t* sh_ws  = (ushort_t*)(ws + WS_SH_OFF);
  ushort_t* wih_bf = (ushort_t*)(ws + WS_WIH_OFF);
  ushort_t* whh_bf = (ushort_t*)(ws + WS_WHH_OFF);
  ushort_t* ggT_bf = (ushort_t*)(ws + WS_GGT_OFF);
  ushort_t* w2_bf  = (ushort_t*)(ws + WS_W2T_OFF);

  prep_all<<<dim3(6346), dim3(256), 0, stream>>>(
      emb, emb_bf, wih, whh, ggnn_w, W2, wih_bf, whh_bf, ggT_bf, w2_bf);

  graph_pipeline<<<dim3(NGRAPH), dim3(256), 0, stream>>>(
      x, ei, ecount, indeg, outdeg, numcount, emb, ggT_bf, ggnn_b,
      wih_bf, whh_bf, bih, bhh, W1, W1b, W2b, qw, qb, W3, W3b, w2_bf, sh_ws);

  final_gemm<<<dim3(2, 782), dim3(256), 0, stream>>>(sh_ws, emb_bf, out);
}